// Round 2
// baseline (720.661 us; speedup 1.0000x reference)
//
#include <hip/hip_runtime.h>
#include <hip/hip_bf16.h>

// Problem constants
#define BN 4
#define MID 128
#define P 1024        // 32*32 spatial
#define PS 1024
#define DSTATE 16
#define DTRANK 64
#define XD 96         // DTRANK + 2*DSTATE
#define HOUT 256

typedef __hip_bfloat16 bf16;

__device__ __forceinline__ float b2f(bf16 v) { return __bfloat162float(v); }

// Generic dual-dtype load
__device__ __forceinline__ float dload(const void* p, size_t i, bool isbf) {
  return isbf ? b2f(((const bf16*)p)[i]) : ((const float*)p)[i];
}

// ---------------- Param pack conversion ----------------
// 24 param tensors (all inputs except x), concatenated as fp32 into ws.
#define NPARAM 24
#define TOTAL_PARAMS 392192
struct PtrPack { const void* p[NPARAM]; };

__global__ void convert_params_kernel(PtrPack pk, const unsigned* __restrict__ alog_raw,
                                      float* __restrict__ dst) {
  bool isbf = (alog_raw[0] != 0u);   // alog0[0]==log(1)==0.0f in fp32 mode
  int tid = blockIdx.x * blockDim.x + threadIdx.x;
  if (tid >= TOTAL_PARAMS) return;
  const int sizes[NPARAM] = {
    16384, 128,
    128, 128, 4608, 256, 128, 98304, 65536, 1024, 16384, 1024,
    128, 128, 4608, 256, 128, 98304, 65536, 1024, 16384, 1024,
    512, 128
  };
  int t = 0, off = tid;
  while (off >= sizes[t]) { off -= sizes[t]; ++t; }
  dst[tid] = dload(pk.p[t], off, isbf);
}

// ---------------- Stage 1: stride-8 8x8 grouped conv (groups=32) ----------------
// x: (4,64,256,256); w: (128,2,8,8) fp32 pack; out h: (4,128,1024) fp32
template <bool ISBF>
__device__ void conv_in_body(const void* __restrict__ x, const float* __restrict__ w,
                             const float* __restrict__ bias, float* __restrict__ h, int tid) {
  int p = tid & 1023; int oc = (tid >> 10) & 127; int b = tid >> 17;
  int oy = p >> 5, ox = p & 31;
  int g = oc >> 2;                      // 4 out-ch per group, 2 in-ch per group
  size_t xbase = ((size_t)b * 64 + g * 2) * 256 * 256;
  const float* wp = w + (size_t)oc * 128;
  float acc = bias[oc];
  for (int i = 0; i < 2; ++i) {
    size_t xc = xbase + (size_t)i * 256 * 256 + (size_t)oy * 8 * 256 + ox * 8;
    const float* wc = wp + i * 64;
#pragma unroll
    for (int kh = 0; kh < 8; ++kh)
#pragma unroll
      for (int kw = 0; kw < 8; ++kw)
        acc += dload(x, xc + kh * 256 + kw, ISBF) * wc[kh * 8 + kw];
  }
  h[tid] = acc;
}

__global__ void conv_in_kernel(const void* __restrict__ x, const unsigned* __restrict__ alog_raw,
                               const float* __restrict__ w, const float* __restrict__ bias,
                               float* __restrict__ h) {
  int tid = blockIdx.x * blockDim.x + threadIdx.x;
  if (tid >= BN * MID * P) return;
  if (alog_raw[0] != 0u) conv_in_body<true>(x, w, bias, h, tid);
  else                   conv_in_body<false>(x, w, bias, h, tid);
}

// ---------------- GroupNorm (2 groups of 64 ch) ----------------
__global__ void groupnorm_kernel(const float* __restrict__ h, const float* __restrict__ gg,
                                 const float* __restrict__ gb, float* __restrict__ hn) {
  int b = blockIdx.x >> 1, grp = blockIdx.x & 1;
  const float* hp = h + ((size_t)b * MID + grp * 64) * P;
  float s = 0.f, s2 = 0.f;
  for (int i = threadIdx.x; i < 64 * P; i += blockDim.x) {
    float v = hp[i]; s += v; s2 += v * v;
  }
  __shared__ float red[256], red2[256];
  red[threadIdx.x] = s; red2[threadIdx.x] = s2; __syncthreads();
  for (int st = 128; st > 0; st >>= 1) {
    if ((int)threadIdx.x < st) { red[threadIdx.x] += red[threadIdx.x + st]; red2[threadIdx.x] += red2[threadIdx.x + st]; }
    __syncthreads();
  }
  float mu = red[0] * (1.f / (64 * P));
  float var = red2[0] * (1.f / (64 * P)) - mu * mu;
  float rs = rsqrtf(var + 1e-5f);
  float* op = hn + ((size_t)b * MID + grp * 64) * P;
  for (int i = threadIdx.x; i < 64 * P; i += blockDim.x) {
    int c = grp * 64 + (i >> 10);
    op[i] = (hp[i] - mu) * rs * gg[c] + gb[c];
  }
}

// ---------------- 3x3 grouped conv (groups=64, 128->256 ch, pad 1) ----------------
__global__ void inproj_kernel(const float* __restrict__ hn, const float* __restrict__ w,
                              float* __restrict__ xr) {
  int tid = blockIdx.x * blockDim.x + threadIdx.x;
  if (tid >= BN * 256 * P) return;
  int p = tid & 1023; int oc = (tid >> 10) & 255; int b = tid >> 18;
  int y = p >> 5, x = p & 31;
  int g = oc >> 2;                     // 4 out-ch per group, 2 in-ch per group
  const float* hb = hn + ((size_t)b * MID + g * 2) * P;
  const float* wp = w + oc * 18;
  float acc = 0.f;
  for (int i = 0; i < 2; ++i) {
    const float* hc = hb + i * P;
    const float* wc = wp + i * 9;
#pragma unroll
    for (int ky = 0; ky < 3; ++ky) {
      int iy = y + ky - 1; if ((unsigned)iy >= 32u) continue;
#pragma unroll
      for (int kx = 0; kx < 3; ++kx) {
        int ix = x + kx - 1; if ((unsigned)ix >= 32u) continue;
        acc += hc[iy * 32 + ix] * wc[ky * 3 + kx];
      }
    }
  }
  xr[tid] = acc;
}

// ---------------- 1x1 grouped conv (groups=64) + SiLU -> u ----------------
__global__ void conv1x1_silu_kernel(const float* __restrict__ xr, const float* __restrict__ w,
                                    const float* __restrict__ bias, float* __restrict__ u) {
  int tid = blockIdx.x * blockDim.x + threadIdx.x;
  if (tid >= BN * MID * P) return;
  int p = tid & 1023; int c = (tid >> 10) & 127; int b = tid >> 17;
  const float* xp = xr + ((size_t)b * 256 + (c & ~1)) * P + p;
  float acc = bias[c] + w[2 * c] * xp[0] + w[2 * c + 1] * xp[P];
  u[tid] = acc / (1.f + __expf(-acc));
}

// ---------------- x_dbl = u @ xproj^T : (4,128,96) ----------------
__global__ void xdbl_kernel(const float* __restrict__ u, const float* __restrict__ xw,
                            float* __restrict__ xd) {
  int bl = blockIdx.x;                 // 512
  __shared__ float us[P];
  const float* up = u + (size_t)bl * P;
  for (int i = threadIdx.x; i < P; i += blockDim.x) us[i] = up[i];
  __syncthreads();
  int k = threadIdx.x;
  if (k < XD) {
    const float* wp = xw + (size_t)k * P;
    float acc = 0.f;
#pragma unroll 4
    for (int i = 0; i < P; ++i) acc += us[i] * wp[i];
    xd[(size_t)bl * XD + k] = acc;
  }
}

// ---------------- delta = softplus(xd[:, :64] @ dtp_w^T + b) : (4,128,1024) ----------------
__global__ void delta_kernel(const float* __restrict__ xd, const float* __restrict__ dw,
                             const float* __restrict__ db, float* __restrict__ dlt) {
  int bl = blockIdx.x;                 // 512
  __shared__ float ds[DTRANK];
  if ((int)threadIdx.x < DTRANK) ds[threadIdx.x] = xd[(size_t)bl * XD + threadIdx.x];
  __syncthreads();
  for (int d = threadIdx.x; d < PS; d += blockDim.x) {
    const float* wp = dw + (size_t)d * DTRANK;
    float acc = db[d];
#pragma unroll 8
    for (int r = 0; r < DTRANK; ++r) acc += ds[r] * wp[r];
    float sp = fmaxf(acc, 0.f) + log1pf(__expf(-fabsf(acc)));
    dlt[(size_t)bl * PS + d] = sp;
  }
}

// ---------------- selective scan: thread per (b,d,n), shuffle-reduce over n ----------------
__global__ void scan_kernel(const float* __restrict__ u, const float* __restrict__ dlt,
                            const float* __restrict__ xd, const float* __restrict__ alog,
                            const float* __restrict__ dd, float* __restrict__ y) {
  int tid = blockIdx.x * blockDim.x + threadIdx.x;  // 65536
  if (tid >= BN * PS * DSTATE) return;
  int n = tid & 15; int d = (tid >> 4) & 1023; int b = tid >> 14;
  float A = -__expf(alog[d * DSTATE + n]);
  float D = dd[d];
  float state = 0.f;
  const float* up = u + (size_t)b * MID * P + d;
  const float* dp = dlt + (size_t)b * MID * PS + d;
  const float* xp = xd + (size_t)b * MID * XD;
  float* yp = y + (size_t)b * MID * P + d;
  for (int l = 0; l < MID; ++l) {
    float dl = dp[(size_t)l * PS];
    float uu = up[(size_t)l * P];
    float Bv = xp[l * XD + DTRANK + n];
    float Cv = xp[l * XD + DTRANK + DSTATE + n];
    float dA = __expf(dl * A);
    state = dA * state + dl * uu * Bv;
    float yv = state * Cv;
    yv += __shfl_xor(yv, 1, 16);
    yv += __shfl_xor(yv, 2, 16);
    yv += __shfl_xor(yv, 4, 16);
    yv += __shfl_xor(yv, 8, 16);
    if (n == 0) yp[(size_t)l * P] = yv + uu * D;
  }
}

// ---------------- h = y * silu(res) + h ----------------
__global__ void merge_kernel(const float* __restrict__ y, const float* __restrict__ xr,
                             float* __restrict__ h) {
  int tid = blockIdx.x * blockDim.x + threadIdx.x;
  if (tid >= BN * MID * P) return;
  int p = tid & 1023; int c = (tid >> 10) & 127; int b = tid >> 17;
  float res = xr[((size_t)b * 256 + 128 + c) * P + p];
  float s = res / (1.f + __expf(-res));
  h[tid] = y[tid] * s + h[tid];
}

// ---------------- 1x1 grouped conv out (groups=32) ----------------
__global__ void convout_kernel(const float* __restrict__ h, const float* __restrict__ w,
                               const float* __restrict__ bias, float* __restrict__ o) {
  int tid = blockIdx.x * blockDim.x + threadIdx.x;
  if (tid >= BN * MID * P) return;
  int p = tid & 1023; int oc = (tid >> 10) & 127; int b = tid >> 17;
  const float* hp = h + ((size_t)b * MID + (oc & ~3)) * P + p;
  const float* wp = w + oc * 4;
  float acc = bias[oc];
#pragma unroll
  for (int i = 0; i < 4; ++i) acc += wp[i] * hp[(size_t)i * P];
  o[tid] = acc;
}

// ---------------- bilinear x8 upsample (half-pixel + edge clamp), dual-dtype store ----------------
__global__ void resize_kernel(const float* __restrict__ o, const unsigned* __restrict__ alog_raw,
                              void* __restrict__ out) {
  int tid = blockIdx.x * blockDim.x + threadIdx.x;  // 4*128*256*256
  if (tid >= BN * MID * HOUT * HOUT) return;
  int ox = tid & 255; int oy = (tid >> 8) & 255; int c = (tid >> 16) & 127; int b = tid >> 23;
  float cx = (ox + 0.5f) * 0.125f - 0.5f;
  float cy = (oy + 0.5f) * 0.125f - 0.5f;
  int ix0 = (int)floorf(cx); float tx = cx - (float)ix0;
  int iy0 = (int)floorf(cy); float ty = cy - (float)iy0;
  int x0 = max(ix0, 0), x1 = min(ix0 + 1, 31);
  int y0 = max(iy0, 0), y1 = min(iy0 + 1, 31);
  const float* ip = o + ((size_t)b * MID + c) * P;
  float v00 = ip[y0 * 32 + x0], v01 = ip[y0 * 32 + x1];
  float v10 = ip[y1 * 32 + x0], v11 = ip[y1 * 32 + x1];
  float v = (1.f - ty) * ((1.f - tx) * v00 + tx * v01) + ty * ((1.f - tx) * v10 + tx * v11);
  if (alog_raw[0] != 0u) ((bf16*)out)[tid] = __float2bfloat16(v);
  else                   ((float*)out)[tid] = v;
}

extern "C" void kernel_launch(void* const* d_in, const int* in_sizes, int n_in,
                              void* d_out, int out_size, void* d_ws, size_t ws_size,
                              hipStream_t stream) {
  const void* x = d_in[0];
  const unsigned* alog_raw = (const unsigned*)d_in[11];  // dtype probe: log(1)=0.0f

  PtrPack pk;
  for (int i = 0; i < NPARAM; ++i) pk.p[i] = d_in[i + 1];

  float* ws = (float*)d_ws;
  float* pp  = ws;                        // param pack, 392192 floats
  float* h   = pp + TOTAL_PARAMS;         // 524288
  float* hn  = h + 524288;                // 524288
  float* xr  = hn + 524288;               // 1048576
  float* u   = xr + 1048576;              // 524288
  float* xd  = u + 524288;                // 49152
  float* dlt = xd + 49152;                // 524288
  float* y   = dlt + 524288;              // 524288
  float* co  = y + 524288;                // 524288

  // fp32 param views into the pack
  const float* w_in  = pp + 0;
  const float* b_in  = pp + 16384;
  const float* w_out = pp + 391552;
  const float* b_out = pp + 392064;
  const float* gn_g[2], *gn_b[2], *inproj_w[2], *conv_w[2], *conv_b[2],
             *xproj_w[2], *dtp_w[2], *dtp_b[2], *alog_f[2], *dd_f[2];
  for (int k = 0; k < 2; ++k) {
    const float* base = pp + 16512 + (size_t)k * 187520;
    gn_g[k] = base + 0;       gn_b[k] = base + 128;
    inproj_w[k] = base + 256; conv_w[k] = base + 4864;
    conv_b[k] = base + 5120;  xproj_w[k] = base + 5248;
    dtp_w[k] = base + 103552; dtp_b[k] = base + 169088;
    alog_f[k] = base + 170112; dd_f[k] = base + 186496;
  }

  convert_params_kernel<<<(TOTAL_PARAMS + 255) / 256, 256, 0, stream>>>(pk, alog_raw, pp);
  conv_in_kernel<<<2048, 256, 0, stream>>>(x, alog_raw, w_in, b_in, h);

  for (int blk = 0; blk < 2; ++blk) {
    groupnorm_kernel<<<8, 256, 0, stream>>>(h, gn_g[blk], gn_b[blk], hn);
    inproj_kernel<<<4096, 256, 0, stream>>>(hn, inproj_w[blk], xr);
    conv1x1_silu_kernel<<<2048, 256, 0, stream>>>(xr, conv_w[blk], conv_b[blk], u);
    xdbl_kernel<<<512, 128, 0, stream>>>(u, xproj_w[blk], xd);
    delta_kernel<<<512, 256, 0, stream>>>(xd, dtp_w[blk], dtp_b[blk], dlt);
    scan_kernel<<<256, 256, 0, stream>>>(u, dlt, xd, alog_f[blk], dd_f[blk], y);
    merge_kernel<<<2048, 256, 0, stream>>>(y, xr, h);
  }

  convout_kernel<<<2048, 256, 0, stream>>>(h, w_out, b_out, co);
  resize_kernel<<<131072, 256, 0, stream>>>(co, alog_raw, d_out);
}

// Round 3
// 580.863 us; speedup vs baseline: 1.2407x; 1.2407x over previous
//
#include <hip/hip_runtime.h>
#include <hip/hip_bf16.h>

// Problem constants
#define BN 4
#define MID 128
#define P 1024        // 32*32 spatial
#define PS 1024
#define DSTATE 16
#define DTRANK 64
#define XD 96         // DTRANK + 2*DSTATE
#define HOUT 256

typedef __hip_bfloat16 bf16;

__device__ __forceinline__ float b2f(bf16 v) { return __bfloat162float(v); }
__device__ __forceinline__ float dload(const void* p, size_t i, bool isbf) {
  return isbf ? b2f(((const bf16*)p)[i]) : ((const float*)p)[i];
}
__device__ __forceinline__ float bfl(unsigned u) {  // low bf16 of a 32-bit pair
  union { unsigned i; float f; } c; c.i = u << 16; return c.f;
}
__device__ __forceinline__ float bfh(unsigned u) {  // high bf16
  union { unsigned i; float f; } c; c.i = u & 0xffff0000u; return c.f;
}

// ---------------- Param pack conversion ----------------
#define NPARAM 24
#define TOTAL_PARAMS 392192
struct PtrPack { const void* p[NPARAM]; };

__global__ void convert_params_kernel(PtrPack pk, const unsigned* __restrict__ alog_raw,
                                      float* __restrict__ dst) {
  bool isbf = (alog_raw[0] != 0u);   // alog0[0]==log(1)==0.0f in fp32 mode
  int tid = blockIdx.x * blockDim.x + threadIdx.x;
  if (tid >= TOTAL_PARAMS) return;
  const int sizes[NPARAM] = {
    16384, 128,
    128, 128, 4608, 256, 128, 98304, 65536, 1024, 16384, 1024,
    128, 128, 4608, 256, 128, 98304, 65536, 1024, 16384, 1024,
    512, 128
  };
  int t = 0, off = tid;
  while (off >= sizes[t]) { off -= sizes[t]; ++t; }
  dst[tid] = dload(pk.p[t], off, isbf);
}

// ---------------- Stage 1: stride-8 8x8 grouped conv (groups=32) ----------------
__global__ void conv_in_kernel(const void* __restrict__ x, const unsigned* __restrict__ alog_raw,
                               const float* __restrict__ w, const float* __restrict__ bias,
                               float* __restrict__ h) {
  int tid = blockIdx.x * blockDim.x + threadIdx.x;
  if (tid >= BN * MID * P) return;
  int p = tid & 1023; int oc = (tid >> 10) & 127; int b = tid >> 17;
  int oy = p >> 5, ox = p & 31;
  int g = oc >> 2;                      // 4 out-ch per group, 2 in-ch per group
  size_t xbase = ((size_t)b * 64 + g * 2) * 65536;   // elements
  const float* wp = w + (size_t)oc * 128;
  float acc = bias[oc];
  if (alog_raw[0] != 0u) {
    // bf16: rows of 8 bf16 = one uint4 (16B)
    const uint4* xp = (const uint4*)x;
    for (int i = 0; i < 2; ++i) {
      size_t cbase = (xbase >> 3) + (size_t)i * 8192 + (size_t)oy * 256 + ox;
      const float* wc = wp + i * 64;
#pragma unroll
      for (int kh = 0; kh < 8; ++kh) {
        uint4 v = xp[cbase + kh * 32];
        const float* wk = wc + kh * 8;
        acc += bfl(v.x)*wk[0] + bfh(v.x)*wk[1] + bfl(v.y)*wk[2] + bfh(v.y)*wk[3]
             + bfl(v.z)*wk[4] + bfh(v.z)*wk[5] + bfl(v.w)*wk[6] + bfh(v.w)*wk[7];
      }
    }
  } else {
    const float* xf = (const float*)x;
    for (int i = 0; i < 2; ++i) {
      size_t cb = xbase + (size_t)i * 65536 + (size_t)oy * 2048 + ox * 8;
      const float* wc = wp + i * 64;
#pragma unroll
      for (int kh = 0; kh < 8; ++kh)
#pragma unroll
        for (int kw = 0; kw < 8; ++kw)
          acc += xf[cb + kh * 256 + kw] * wc[kh * 8 + kw];
    }
  }
  h[tid] = acc;
}

// ---------------- GroupNorm stats: partial sums then tiny reduce ----------------
// h: (4,128,1024) = 8 groups x 65536 contiguous. 128 blocks x 4096 elems.
__global__ void gn_stats1(const float* __restrict__ h, float* __restrict__ partial) {
  const float4* hp = (const float4*)(h + (size_t)blockIdx.x * 4096);
  float s = 0.f, s2 = 0.f;
  for (int i = threadIdx.x; i < 1024; i += 256) {
    float4 v = hp[i];
    s  += v.x + v.y + v.z + v.w;
    s2 += v.x*v.x + v.y*v.y + v.z*v.z + v.w*v.w;
  }
#pragma unroll
  for (int off = 32; off > 0; off >>= 1) { s += __shfl_xor(s, off); s2 += __shfl_xor(s2, off); }
  __shared__ float ls[4], ls2[4];
  int wid = threadIdx.x >> 6;
  if ((threadIdx.x & 63) == 0) { ls[wid] = s; ls2[wid] = s2; }
  __syncthreads();
  if (threadIdx.x == 0) {
    partial[blockIdx.x * 2]     = ls[0] + ls[1] + ls[2] + ls[3];
    partial[blockIdx.x * 2 + 1] = ls2[0] + ls2[1] + ls2[2] + ls2[3];
  }
}

__global__ void gn_stats2(const float* __restrict__ partial, float* __restrict__ stats) {
  int t = threadIdx.x;
  if (t < 16) {          // t = bg*2 + comp; 16 blocks per bg
    int bg = t >> 1, comp = t & 1;
    float s = 0.f;
#pragma unroll
    for (int i = 0; i < 16; ++i) s += partial[(bg * 16 + i) * 2 + comp];
    stats[t] = s;
  }
}

// ---------------- fused: GN-apply + 3x3 grouped conv (xs half) + 1x1 conv + SiLU -> u ----------------
__global__ void fused_u_kernel(const float* __restrict__ h, const float* __restrict__ stats,
                               const float* __restrict__ gng, const float* __restrict__ gnb,
                               const float* __restrict__ iw, const float* __restrict__ cw,
                               const float* __restrict__ cb, float* __restrict__ u) {
  int tid = blockIdx.x * blockDim.x + threadIdx.x;
  if (tid >= BN * MID * P) return;
  int p = tid & 1023; int c = (tid >> 10) & 127; int b = tid >> 17;
  int y = p >> 5, x = p & 31;
  int ic0 = c & ~1;                       // 2 input channels of this group
  int bg = b * 2 + (ic0 >> 6);
  float mu = stats[bg * 2] * (1.f / 65536.f);
  float var = stats[bg * 2 + 1] * (1.f / 65536.f) - mu * mu;
  float rs = rsqrtf(var + 1e-5f);
  float a0 = rs * gng[ic0],     o0 = gnb[ic0]     - mu * a0;
  float a1 = rs * gng[ic0 + 1], o1 = gnb[ic0 + 1] - mu * a1;
  const float* h0 = h + ((size_t)b * MID + ic0) * P;
  const float* h1 = h0 + P;
  const float* w0 = iw + (size_t)(2 * c) * 18;
  const float* w1 = w0 + 18;
  float xs0 = 0.f, xs1 = 0.f;
#pragma unroll
  for (int ky = 0; ky < 3; ++ky) {
    int iy = y + ky - 1; if ((unsigned)iy >= 32u) continue;
#pragma unroll
    for (int kx = 0; kx < 3; ++kx) {
      int ix = x + kx - 1; if ((unsigned)ix >= 32u) continue;
      int wi = ky * 3 + kx;
      float v0 = h0[iy * 32 + ix] * a0 + o0;
      float v1 = h1[iy * 32 + ix] * a1 + o1;
      xs0 += v0 * w0[wi] + v1 * w0[9 + wi];
      xs1 += v0 * w1[wi] + v1 * w1[9 + wi];
    }
  }
  float acc = cb[c] + cw[2 * c] * xs0 + cw[2 * c + 1] * xs1;
  u[tid] = acc / (1.f + __expf(-acc));
}

// ---------------- x_dbl = u @ xproj^T : (4,128,96) ----------------
__global__ void xdbl_kernel(const float* __restrict__ u, const float* __restrict__ xw,
                            float* __restrict__ xd) {
  int bl = blockIdx.x;                 // 512
  __shared__ float4 us[256];
  const float4* up = (const float4*)(u + (size_t)bl * P);
  for (int i = threadIdx.x; i < 256; i += blockDim.x) us[i] = up[i];
  __syncthreads();
  int k = threadIdx.x;
  if (k < XD) {
    const float4* wp = (const float4*)(xw + (size_t)k * P);
    float a0 = 0.f, a1 = 0.f, a2 = 0.f, a3 = 0.f;
#pragma unroll 4
    for (int i = 0; i < 256; ++i) {
      float4 uu = us[i], ww = wp[i];
      a0 += uu.x * ww.x; a1 += uu.y * ww.y; a2 += uu.z * ww.z; a3 += uu.w * ww.w;
    }
    xd[(size_t)bl * XD + k] = (a0 + a1) + (a2 + a3);
  }
}

// ---------------- delta = softplus(xd[:, :64] @ dtp_w^T + b) ----------------
__global__ void delta_kernel(const float* __restrict__ xd, const float* __restrict__ dw,
                             const float* __restrict__ db, float* __restrict__ dlt) {
  int bl = blockIdx.x;                 // 512
  __shared__ float4 ds[16];
  if (threadIdx.x < 16) ds[threadIdx.x] = ((const float4*)(xd + (size_t)bl * XD))[threadIdx.x];
  __syncthreads();
  for (int d = threadIdx.x; d < PS; d += blockDim.x) {
    const float4* wp = (const float4*)(dw + (size_t)d * DTRANK);
    float acc = db[d];
#pragma unroll
    for (int r = 0; r < 16; ++r) {
      float4 w4 = wp[r], d4 = ds[r];
      acc += d4.x * w4.x + d4.y * w4.y + d4.z * w4.z + d4.w * w4.w;
    }
    float sp = fmaxf(acc, 0.f) + log1pf(__expf(-fabsf(acc)));
    dlt[(size_t)bl * PS + d] = sp;
  }
}

// ---------------- selective scan: thread per (b,d,n), shuffle-reduce over n ----------------
__global__ void scan_kernel(const float* __restrict__ u, const float* __restrict__ dlt,
                            const float* __restrict__ xd, const float* __restrict__ alog,
                            const float* __restrict__ dd, float* __restrict__ y) {
  int tid = blockIdx.x * blockDim.x + threadIdx.x;  // 65536
  if (tid >= BN * PS * DSTATE) return;
  int n = tid & 15; int d = (tid >> 4) & 1023; int b = tid >> 14;
  float A = -__expf(alog[d * DSTATE + n]);
  float D = dd[d];
  float state = 0.f;
  const float* up = u + (size_t)b * MID * P + d;
  const float* dp = dlt + (size_t)b * MID * PS + d;
  const float* xp = xd + (size_t)b * MID * XD;
  float* yp = y + (size_t)b * MID * P + d;
#pragma unroll 2
  for (int l = 0; l < MID; ++l) {
    float dl = dp[(size_t)l * PS];
    float uu = up[(size_t)l * P];
    float Bv = xp[l * XD + DTRANK + n];
    float Cv = xp[l * XD + DTRANK + DSTATE + n];
    float dA = __expf(dl * A);
    state = dA * state + dl * uu * Bv;
    float yv = state * Cv;
    yv += __shfl_xor(yv, 1, 16);
    yv += __shfl_xor(yv, 2, 16);
    yv += __shfl_xor(yv, 4, 16);
    yv += __shfl_xor(yv, 8, 16);
    if (n == 0) yp[(size_t)l * P] = yv + uu * D;
  }
}

// ---------------- fused: res-conv (GN-applied) + silu + y*res + residual ----------------
__global__ void merge_res_kernel(const float* __restrict__ hin, const float* __restrict__ stats,
                                 const float* __restrict__ gng, const float* __restrict__ gnb,
                                 const float* __restrict__ iw, const float* __restrict__ y_,
                                 float* __restrict__ hout) {
  int tid = blockIdx.x * blockDim.x + threadIdx.x;
  if (tid >= BN * MID * P) return;
  int p = tid & 1023; int c = (tid >> 10) & 127; int b = tid >> 17;
  int y = p >> 5, x = p & 31;
  int oc = 128 + c;
  int ic0 = (oc >> 2) * 2;              // in [64,128) -> GN group 1
  int bg = b * 2 + 1;
  float mu = stats[bg * 2] * (1.f / 65536.f);
  float var = stats[bg * 2 + 1] * (1.f / 65536.f) - mu * mu;
  float rs = rsqrtf(var + 1e-5f);
  float a0 = rs * gng[ic0],     o0 = gnb[ic0]     - mu * a0;
  float a1 = rs * gng[ic0 + 1], o1 = gnb[ic0 + 1] - mu * a1;
  const float* h0 = hin + ((size_t)b * MID + ic0) * P;
  const float* h1 = h0 + P;
  const float* w = iw + (size_t)oc * 18;
  float res = 0.f;
#pragma unroll
  for (int ky = 0; ky < 3; ++ky) {
    int iy = y + ky - 1; if ((unsigned)iy >= 32u) continue;
#pragma unroll
    for (int kx = 0; kx < 3; ++kx) {
      int ix = x + kx - 1; if ((unsigned)ix >= 32u) continue;
      int wi = ky * 3 + kx;
      res += (h0[iy * 32 + ix] * a0 + o0) * w[wi] + (h1[iy * 32 + ix] * a1 + o1) * w[9 + wi];
    }
  }
  float s = res / (1.f + __expf(-res));
  hout[tid] = y_[tid] * s + hin[tid];
}

// ---------------- 1x1 grouped conv out (groups=32) ----------------
__global__ void convout_kernel(const float* __restrict__ h, const float* __restrict__ w,
                               const float* __restrict__ bias, float* __restrict__ o) {
  int tid = blockIdx.x * blockDim.x + threadIdx.x;
  if (tid >= BN * MID * P) return;
  int p = tid & 1023; int oc = (tid >> 10) & 127; int b = tid >> 17;
  const float* hp = h + ((size_t)b * MID + (oc & ~3)) * P + p;
  const float* wp = w + oc * 4;
  float acc = bias[oc];
#pragma unroll
  for (int i = 0; i < 4; ++i) acc += wp[i] * hp[(size_t)i * P];
  o[tid] = acc;
}

// ---------------- bilinear x8 upsample, 4 outputs/thread ----------------
__global__ void resize_kernel(const float* __restrict__ o, const unsigned* __restrict__ alog_raw,
                              void* __restrict__ out) {
  int tid = blockIdx.x * blockDim.x + threadIdx.x;  // 8388608 threads, 4 outputs each
  if (tid >= BN * MID * HOUT * HOUT / 4) return;
  int xq = tid & 63; int oy = (tid >> 6) & 255; int c = (tid >> 14) & 127; int b = tid >> 21;
  float cy = (oy + 0.5f) * 0.125f - 0.5f;
  int iy0 = (int)floorf(cy); float ty = cy - (float)iy0;
  int y0 = max(iy0, 0), y1 = min(iy0 + 1, 31);
  const float* ip = o + ((size_t)b * MID + c) * P;
  float v[4];
#pragma unroll
  for (int j = 0; j < 4; ++j) {
    int ox = xq * 4 + j;
    float cx = (ox + 0.5f) * 0.125f - 0.5f;
    int ix0 = (int)floorf(cx); float tx = cx - (float)ix0;
    int x0 = max(ix0, 0), x1 = min(ix0 + 1, 31);
    float v00 = ip[y0 * 32 + x0], v01 = ip[y0 * 32 + x1];
    float v10 = ip[y1 * 32 + x0], v11 = ip[y1 * 32 + x1];
    v[j] = (1.f - ty) * ((1.f - tx) * v00 + tx * v01) + ty * ((1.f - tx) * v10 + tx * v11);
  }
  if (alog_raw[0] != 0u) {
    ushort4 s;
    s.x = __hip_bfloat16_raw(__float2bfloat16(v[0])).x;
    s.y = __hip_bfloat16_raw(__float2bfloat16(v[1])).x;
    s.z = __hip_bfloat16_raw(__float2bfloat16(v[2])).x;
    s.w = __hip_bfloat16_raw(__float2bfloat16(v[3])).x;
    ((ushort4*)out)[tid] = s;
  } else {
    ((float4*)out)[tid] = make_float4(v[0], v[1], v[2], v[3]);
  }
}

extern "C" void kernel_launch(void* const* d_in, const int* in_sizes, int n_in,
                              void* d_out, int out_size, void* d_ws, size_t ws_size,
                              hipStream_t stream) {
  const void* x = d_in[0];
  const unsigned* alog_raw = (const unsigned*)d_in[11];  // dtype probe: log(1)=0.0f

  PtrPack pk;
  for (int i = 0; i < NPARAM; ++i) pk.p[i] = d_in[i + 1];

  float* ws = (float*)d_ws;
  float* pp   = ws;                       // param pack, 392192 floats
  float* h0   = pp + TOTAL_PARAMS;        // 524288
  float* h1   = h0 + 524288;              // 524288
  float* u    = h1 + 524288;              // 524288
  float* xd   = u + 524288;               // 49152
  float* dlt  = xd + 49152;               // 524288
  float* yb   = dlt + 524288;             // 524288
  float* co   = yb + 524288;              // 524288
  float* part = co + 524288;              // 256
  float* stats= part + 256;               // 16

  // fp32 param views into the pack
  const float* w_in  = pp + 0;
  const float* b_in  = pp + 16384;
  const float* w_out = pp + 391552;
  const float* b_out = pp + 392064;
  const float* gn_g[2], *gn_b[2], *inproj_w[2], *conv_w[2], *conv_b[2],
             *xproj_w[2], *dtp_w[2], *dtp_b[2], *alog_f[2], *dd_f[2];
  for (int k = 0; k < 2; ++k) {
    const float* base = pp + 16512 + (size_t)k * 187520;
    gn_g[k] = base + 0;       gn_b[k] = base + 128;
    inproj_w[k] = base + 256; conv_w[k] = base + 4864;
    conv_b[k] = base + 5120;  xproj_w[k] = base + 5248;
    dtp_w[k] = base + 103552; dtp_b[k] = base + 169088;
    alog_f[k] = base + 170112; dd_f[k] = base + 186496;
  }

  convert_params_kernel<<<(TOTAL_PARAMS + 255) / 256, 256, 0, stream>>>(pk, alog_raw, pp);
  conv_in_kernel<<<2048, 256, 0, stream>>>(x, alog_raw, w_in, b_in, h0);

  float* hbuf[2] = { h0, h1 };
  for (int blk = 0; blk < 2; ++blk) {
    float* hin  = hbuf[blk & 1];
    float* hout = hbuf[(blk + 1) & 1];
    gn_stats1<<<128, 256, 0, stream>>>(hin, part);
    gn_stats2<<<1, 64, 0, stream>>>(part, stats);
    fused_u_kernel<<<2048, 256, 0, stream>>>(hin, stats, gn_g[blk], gn_b[blk],
                                             inproj_w[blk], conv_w[blk], conv_b[blk], u);
    xdbl_kernel<<<512, 128, 0, stream>>>(u, xproj_w[blk], xd);
    delta_kernel<<<512, 256, 0, stream>>>(xd, dtp_w[blk], dtp_b[blk], dlt);
    scan_kernel<<<256, 256, 0, stream>>>(u, dlt, xd, alog_f[blk], dd_f[blk], yb);
    merge_res_kernel<<<2048, 256, 0, stream>>>(hin, stats, gn_g[blk], gn_b[blk],
                                               inproj_w[blk], yb, hout);
  }

  convout_kernel<<<2048, 256, 0, stream>>>(h0, w_out, b_out, co);
  resize_kernel<<<32768, 256, 0, stream>>>(co, alog_raw, d_out);
}

// Round 4
// 477.964 us; speedup vs baseline: 1.5078x; 1.2153x over previous
//
#include <hip/hip_runtime.h>
#include <hip/hip_bf16.h>

// Problem constants
#define BN 4
#define MID 128
#define P 1024        // 32*32 spatial
#define PS 1024
#define DSTATE 16
#define DTRANK 64
#define XD 96         // DTRANK + 2*DSTATE
#define HOUT 256

typedef __hip_bfloat16 bf16;

__device__ __forceinline__ float b2f(bf16 v) { return __bfloat162float(v); }
__device__ __forceinline__ float dload(const void* p, size_t i, bool isbf) {
  return isbf ? b2f(((const bf16*)p)[i]) : ((const float*)p)[i];
}
__device__ __forceinline__ float bfl(unsigned u) {  // low bf16 of a 32-bit pair
  union { unsigned i; float f; } c; c.i = u << 16; return c.f;
}
__device__ __forceinline__ float bfh(unsigned u) {  // high bf16
  union { unsigned i; float f; } c; c.i = u & 0xffff0000u; return c.f;
}

// ---------------- Param pack conversion ----------------
#define NPARAM 24
#define TOTAL_PARAMS 392192
struct PtrPack { const void* p[NPARAM]; };

__global__ void convert_params_kernel(PtrPack pk, const unsigned* __restrict__ alog_raw,
                                      float* __restrict__ dst) {
  bool isbf = (alog_raw[0] != 0u);   // alog0[0]==log(1)==0.0f in fp32 mode
  int tid = blockIdx.x * blockDim.x + threadIdx.x;
  if (tid >= TOTAL_PARAMS) return;
  const int sizes[NPARAM] = {
    16384, 128,
    128, 128, 4608, 256, 128, 98304, 65536, 1024, 16384, 1024,
    128, 128, 4608, 256, 128, 98304, 65536, 1024, 16384, 1024,
    512, 128
  };
  int t = 0, off = tid;
  while (off >= sizes[t]) { off -= sizes[t]; ++t; }
  dst[tid] = dload(pk.p[t], off, isbf);
}

// ---------------- Stage 1: stride-8 8x8 grouped conv (groups=32) ----------------
// One thread computes all 4 output channels of one group at one pixel:
// x is read exactly once from global; weights staged in LDS (block-uniform).
__global__ void conv_in_kernel(const void* __restrict__ x, const unsigned* __restrict__ alog_raw,
                               const float* __restrict__ w, const float* __restrict__ bias,
                               float* __restrict__ h) {
  __shared__ float wlds[512];   // [i][kh][j][kw]
  __shared__ float blds[4];
  int tid = blockIdx.x * 256 + threadIdx.x;   // 131072 total
  int p = tid & 1023; int g = (tid >> 10) & 31; int b = tid >> 15;  // g,b block-uniform
  for (int t = threadIdx.x; t < 512; t += 256) {
    int i = t >> 8, kh = (t >> 5) & 7, j = (t >> 3) & 3, kw = t & 7;
    wlds[t] = w[(g * 4 + j) * 128 + i * 64 + kh * 8 + kw];
  }
  if (threadIdx.x < 4) blds[threadIdx.x] = bias[g * 4 + threadIdx.x];
  __syncthreads();
  int oy = p >> 5, ox = p & 31;
  float acc0 = blds[0], acc1 = blds[1], acc2 = blds[2], acc3 = blds[3];
  if (alog_raw[0] != 0u) {
    const uint4* xp = (const uint4*)x;       // 8 bf16 per uint4
    size_t base = ((size_t)b * 64 + g * 2) * 8192;
    for (int i = 0; i < 2; ++i) {
      size_t cb = base + (size_t)i * 8192 + (size_t)oy * 256 + ox;
#pragma unroll
      for (int kh = 0; kh < 8; ++kh) {
        uint4 v = xp[cb + kh * 32];
        float xv[8] = {bfl(v.x),bfh(v.x),bfl(v.y),bfh(v.y),bfl(v.z),bfh(v.z),bfl(v.w),bfh(v.w)};
        const float* wk = &wlds[(i * 8 + kh) * 32];
#pragma unroll
        for (int kw = 0; kw < 8; ++kw) {
          float xvv = xv[kw];
          acc0 += xvv * wk[kw];
          acc1 += xvv * wk[8 + kw];
          acc2 += xvv * wk[16 + kw];
          acc3 += xvv * wk[24 + kw];
        }
      }
    }
  } else {
    const float4* xf = (const float4*)x;
    size_t base = ((size_t)b * 64 + g * 2) * 16384;
    for (int i = 0; i < 2; ++i) {
      size_t cb = base + (size_t)i * 16384 + (size_t)oy * 512 + ox * 2;
#pragma unroll
      for (int kh = 0; kh < 8; ++kh) {
        float4 v0 = xf[cb + kh * 64];
        float4 v1 = xf[cb + kh * 64 + 1];
        float xv[8] = {v0.x,v0.y,v0.z,v0.w,v1.x,v1.y,v1.z,v1.w};
        const float* wk = &wlds[(i * 8 + kh) * 32];
#pragma unroll
        for (int kw = 0; kw < 8; ++kw) {
          float xvv = xv[kw];
          acc0 += xvv * wk[kw];
          acc1 += xvv * wk[8 + kw];
          acc2 += xvv * wk[16 + kw];
          acc3 += xvv * wk[24 + kw];
        }
      }
    }
  }
  size_t ob = ((size_t)b * 128 + g * 4) * 1024 + p;
  h[ob] = acc0; h[ob + 1024] = acc1; h[ob + 2048] = acc2; h[ob + 3072] = acc3;
}

// ---------------- GroupNorm partial sums (128 blocks x 4096 elems) ----------------
__global__ void gn_stats1(const float* __restrict__ h, float* __restrict__ partial) {
  const float4* hp = (const float4*)(h + (size_t)blockIdx.x * 4096);
  float s = 0.f, s2 = 0.f;
  for (int i = threadIdx.x; i < 1024; i += 256) {
    float4 v = hp[i];
    s  += v.x + v.y + v.z + v.w;
    s2 += v.x*v.x + v.y*v.y + v.z*v.z + v.w*v.w;
  }
#pragma unroll
  for (int off = 32; off > 0; off >>= 1) { s += __shfl_xor(s, off); s2 += __shfl_xor(s2, off); }
  __shared__ float ls[4], ls2[4];
  int wid = threadIdx.x >> 6;
  if ((threadIdx.x & 63) == 0) { ls[wid] = s; ls2[wid] = s2; }
  __syncthreads();
  if (threadIdx.x == 0) {
    partial[blockIdx.x * 2]     = ls[0] + ls[1] + ls[2] + ls[3];
    partial[blockIdx.x * 2 + 1] = ls2[0] + ls2[1] + ls2[2] + ls2[3];
  }
}

// ---------------- fused: GN-apply + 3x3 conv (xs rows of group g3) + 1x1 + SiLU -> u ----------------
// block = (b, g3, half). Loads h channels 2*g3, 2*g3+1 GN-applied into padded LDS tile,
// computes u channels [4*g3, 4*g3+4).
__global__ void fused_u_kernel(const float* __restrict__ h, const float* __restrict__ partial,
                               const float* __restrict__ gng, const float* __restrict__ gnb,
                               const float* __restrict__ iw, const float* __restrict__ cw,
                               const float* __restrict__ cb, float* __restrict__ u) {
  int blk = blockIdx.x;                 // 256 = b*64 + g3*2 + h2
  int h2 = blk & 1, g3 = (blk >> 1) & 31, b = blk >> 6;
  int ic0 = g3 * 2;
  int bg = b * 2 + (ic0 >> 6);
  __shared__ float tile[2][34][36];
  __shared__ float sred[2];
  if (threadIdx.x < 2) {
    float s = 0.f;
#pragma unroll
    for (int i = 0; i < 16; ++i) s += partial[(bg * 16 + i) * 2 + (int)threadIdx.x];
    sred[threadIdx.x] = s;
  }
  for (int t = threadIdx.x; t < 2448; t += 256) ((float*)tile)[t] = 0.f;
  __syncthreads();
  float mu = sred[0] * (1.f / 65536.f);
  float var = sred[1] * (1.f / 65536.f) - mu * mu;
  float rs = rsqrtf(var + 1e-5f);
  float a0 = rs * gng[ic0],     o0 = gnb[ic0]     - mu * a0;
  float a1 = rs * gng[ic0 + 1], o1 = gnb[ic0 + 1] - mu * a1;
  const float* h0 = h + ((size_t)b * MID + ic0) * P;
  for (int t = threadIdx.x; t < 2048; t += 256) {
    int ch = t >> 10, px = t & 1023, y = px >> 5, xx = px & 31;
    float v = h0[ch * P + px];
    tile[ch][y + 1][xx + 1] = ch ? (v * a1 + o1) : (v * a0 + o0);
  }
  __syncthreads();
  // weights for the 4 xs rows of group g3 (block-uniform -> scalar)
  const float* w0 = iw + (size_t)(4 * g3) * 18;
#pragma unroll
  for (int q = 0; q < 2; ++q) {
    int px = h2 * 512 + q * 256 + threadIdx.x;
    int y = px >> 5, xx = px & 31;
    float nb0[9], nb1[9];
#pragma unroll
    for (int ky = 0; ky < 3; ++ky)
#pragma unroll
      for (int kx = 0; kx < 3; ++kx) {
        nb0[ky * 3 + kx] = tile[0][y + ky][xx + kx];
        nb1[ky * 3 + kx] = tile[1][y + ky][xx + kx];
      }
    float xsv[4];
#pragma unroll
    for (int s4 = 0; s4 < 4; ++s4) {
      const float* wr = w0 + s4 * 18;
      float acc = 0.f;
#pragma unroll
      for (int k = 0; k < 9; ++k) acc += nb0[k] * wr[k] + nb1[k] * wr[9 + k];
      xsv[s4] = acc;
    }
#pragma unroll
    for (int j = 0; j < 4; ++j) {
      int c = 4 * g3 + j;
      int e4 = (j >> 1) * 2;            // xs pair used by conv1x1 out c
      float acc = cb[c] + cw[2 * c] * xsv[e4] + cw[2 * c + 1] * xsv[e4 + 1];
      u[((size_t)b * MID + c) * P + px] = acc / (1.f + __expf(-acc));
    }
  }
}

// ---------------- fused: x_dbl (96 dots) + delta (softplus proj) per (b,l) row ----------------
__global__ void xdbl_delta_kernel(const float* __restrict__ u, const float* __restrict__ xw,
                                  const float* __restrict__ dw, const float* __restrict__ db,
                                  float* __restrict__ xd, float* __restrict__ dlt) {
  int bl = blockIdx.x;                 // 512
  __shared__ float4 us[256];
  __shared__ float xds[DTRANK];
  const float4* up = (const float4*)(u + (size_t)bl * P);
  if (threadIdx.x < 256) us[threadIdx.x] = up[threadIdx.x];
  __syncthreads();
  int k = threadIdx.x;
  if (k < XD) {
    const float4* wp = (const float4*)(xw + (size_t)k * P);
    float a0 = 0.f, a1 = 0.f, a2 = 0.f, a3 = 0.f;
#pragma unroll 4
    for (int i = 0; i < 256; ++i) {
      float4 uu = us[i], ww = wp[i];
      a0 += uu.x * ww.x; a1 += uu.y * ww.y; a2 += uu.z * ww.z; a3 += uu.w * ww.w;
    }
    float v = (a0 + a1) + (a2 + a3);
    xd[(size_t)bl * XD + k] = v;
    if (k < DTRANK) xds[k] = v;
  }
  __syncthreads();
  for (int d = threadIdx.x; d < PS; d += blockDim.x) {
    const float4* wp = (const float4*)(dw + (size_t)d * DTRANK);
    const float4* d4p = (const float4*)xds;
    float acc = db[d];
#pragma unroll
    for (int r = 0; r < 16; ++r) {
      float4 w4 = wp[r], d4 = d4p[r];
      acc += d4.x * w4.x + d4.y * w4.y + d4.z * w4.z + d4.w * w4.w;
    }
    float sp = fmaxf(acc, 0.f) + log1pf(__expf(-fabsf(acc)));
    dlt[(size_t)bl * PS + d] = sp;
  }
}

// ---------------- selective scan: thread per (b,d,n), shuffle-reduce over n ----------------
__global__ void scan_kernel(const float* __restrict__ u, const float* __restrict__ dlt,
                            const float* __restrict__ xd, const float* __restrict__ alog,
                            const float* __restrict__ dd, float* __restrict__ y) {
  int tid = blockIdx.x * blockDim.x + threadIdx.x;  // 65536
  if (tid >= BN * PS * DSTATE) return;
  int n = tid & 15; int d = (tid >> 4) & 1023; int b = tid >> 14;
  float A = -__expf(alog[d * DSTATE + n]);
  float D = dd[d];
  float state = 0.f;
  const float* up = u + (size_t)b * MID * P + d;
  const float* dp = dlt + (size_t)b * MID * PS + d;
  const float* xp = xd + (size_t)b * MID * XD;
  float* yp = y + (size_t)b * MID * P + d;
#pragma unroll 2
  for (int l = 0; l < MID; ++l) {
    float dl = dp[(size_t)l * PS];
    float uu = up[(size_t)l * P];
    float Bv = xp[l * XD + DTRANK + n];
    float Cv = xp[l * XD + DTRANK + DSTATE + n];
    float dA = __expf(dl * A);
    state = dA * state + dl * uu * Bv;
    float yv = state * Cv;
    yv += __shfl_xor(yv, 1, 16);
    yv += __shfl_xor(yv, 2, 16);
    yv += __shfl_xor(yv, 4, 16);
    yv += __shfl_xor(yv, 8, 16);
    if (n == 0) yp[(size_t)l * P] = yv + uu * D;
  }
}

// ---------------- fused: res-conv (GN-applied, LDS tile) + silu + y*res + residual ----------------
// block = (b, gq, half); inproj group g = 32+gq; outputs c = 4*gq+j.
__global__ void merge_res_kernel(const float* __restrict__ hin, const float* __restrict__ partial,
                                 const float* __restrict__ gng, const float* __restrict__ gnb,
                                 const float* __restrict__ iw, const float* __restrict__ y_,
                                 float* __restrict__ hout) {
  int blk = blockIdx.x;                 // 256 = b*64 + gq*2 + h2
  int h2 = blk & 1, gq = (blk >> 1) & 31, b = blk >> 6;
  int g = 32 + gq;
  int ic0 = g * 2;                      // in [64,128) -> GN group 1
  int bg = b * 2 + 1;
  __shared__ float tile[2][34][36];
  __shared__ float sred[2];
  if (threadIdx.x < 2) {
    float s = 0.f;
#pragma unroll
    for (int i = 0; i < 16; ++i) s += partial[(bg * 16 + i) * 2 + (int)threadIdx.x];
    sred[threadIdx.x] = s;
  }
  for (int t = threadIdx.x; t < 2448; t += 256) ((float*)tile)[t] = 0.f;
  __syncthreads();
  float mu = sred[0] * (1.f / 65536.f);
  float var = sred[1] * (1.f / 65536.f) - mu * mu;
  float rs = rsqrtf(var + 1e-5f);
  float a0 = rs * gng[ic0],     o0 = gnb[ic0]     - mu * a0;
  float a1 = rs * gng[ic0 + 1], o1 = gnb[ic0 + 1] - mu * a1;
  const float* h0 = hin + ((size_t)b * MID + ic0) * P;
  for (int t = threadIdx.x; t < 2048; t += 256) {
    int ch = t >> 10, px = t & 1023, y = px >> 5, xx = px & 31;
    float v = h0[ch * P + px];
    tile[ch][y + 1][xx + 1] = ch ? (v * a1 + o1) : (v * a0 + o0);
  }
  __syncthreads();
  const float* w0 = iw + (size_t)(4 * g) * 18;     // 4 res rows of this group
#pragma unroll
  for (int q = 0; q < 2; ++q) {
    int px = h2 * 512 + q * 256 + threadIdx.x;
    int y = px >> 5, xx = px & 31;
    float nb0[9], nb1[9];
#pragma unroll
    for (int ky = 0; ky < 3; ++ky)
#pragma unroll
      for (int kx = 0; kx < 3; ++kx) {
        nb0[ky * 3 + kx] = tile[0][y + ky][xx + kx];
        nb1[ky * 3 + kx] = tile[1][y + ky][xx + kx];
      }
#pragma unroll
    for (int j = 0; j < 4; ++j) {
      const float* wr = w0 + j * 18;
      float res = 0.f;
#pragma unroll
      for (int k = 0; k < 9; ++k) res += nb0[k] * wr[k] + nb1[k] * wr[9 + k];
      int c = 4 * gq + j;
      size_t oi = ((size_t)b * MID + c) * P + px;
      float s = res / (1.f + __expf(-res));
      hout[oi] = y_[oi] * s + hin[oi];
    }
  }
}

// ---------------- 1x1 grouped conv out (groups=32) ----------------
__global__ void convout_kernel(const float* __restrict__ h, const float* __restrict__ w,
                               const float* __restrict__ bias, float* __restrict__ o) {
  int tid = blockIdx.x * blockDim.x + threadIdx.x;
  if (tid >= BN * MID * P) return;
  int p = tid & 1023; int oc = (tid >> 10) & 127; int b = tid >> 17;
  const float* hp = h + ((size_t)b * MID + (oc & ~3)) * P + p;
  const float* wp = w + oc * 4;
  float acc = bias[oc];
#pragma unroll
  for (int i = 0; i < 4; ++i) acc += wp[i] * hp[(size_t)i * P];
  o[tid] = acc;
}

// ---------------- bilinear x8 upsample, 4 outputs/thread ----------------
__global__ void resize_kernel(const float* __restrict__ o, const unsigned* __restrict__ alog_raw,
                              void* __restrict__ out) {
  int tid = blockIdx.x * blockDim.x + threadIdx.x;
  if (tid >= BN * MID * HOUT * HOUT / 4) return;
  int xq = tid & 63; int oy = (tid >> 6) & 255; int c = (tid >> 14) & 127; int b = tid >> 21;
  float cy = (oy + 0.5f) * 0.125f - 0.5f;
  int iy0 = (int)floorf(cy); float ty = cy - (float)iy0;
  int y0 = max(iy0, 0), y1 = min(iy0 + 1, 31);
  const float* ip = o + ((size_t)b * MID + c) * P;
  float v[4];
#pragma unroll
  for (int j = 0; j < 4; ++j) {
    int ox = xq * 4 + j;
    float cx = (ox + 0.5f) * 0.125f - 0.5f;
    int ix0 = (int)floorf(cx); float tx = cx - (float)ix0;
    int x0 = max(ix0, 0), x1 = min(ix0 + 1, 31);
    float v00 = ip[y0 * 32 + x0], v01 = ip[y0 * 32 + x1];
    float v10 = ip[y1 * 32 + x0], v11 = ip[y1 * 32 + x1];
    v[j] = (1.f - ty) * ((1.f - tx) * v00 + tx * v01) + ty * ((1.f - tx) * v10 + tx * v11);
  }
  if (alog_raw[0] != 0u) {
    ushort4 s;
    s.x = __hip_bfloat16_raw(__float2bfloat16(v[0])).x;
    s.y = __hip_bfloat16_raw(__float2bfloat16(v[1])).x;
    s.z = __hip_bfloat16_raw(__float2bfloat16(v[2])).x;
    s.w = __hip_bfloat16_raw(__float2bfloat16(v[3])).x;
    ((ushort4*)out)[tid] = s;
  } else {
    ((float4*)out)[tid] = make_float4(v[0], v[1], v[2], v[3]);
  }
}

extern "C" void kernel_launch(void* const* d_in, const int* in_sizes, int n_in,
                              void* d_out, int out_size, void* d_ws, size_t ws_size,
                              hipStream_t stream) {
  const void* x = d_in[0];
  const unsigned* alog_raw = (const unsigned*)d_in[11];  // dtype probe: log(1)=0.0f

  PtrPack pk;
  for (int i = 0; i < NPARAM; ++i) pk.p[i] = d_in[i + 1];

  float* ws = (float*)d_ws;
  float* pp   = ws;                       // param pack, 392192 floats
  float* h0   = pp + TOTAL_PARAMS;        // 524288
  float* h1   = h0 + 524288;              // 524288
  float* u    = h1 + 524288;              // 524288
  float* xd   = u + 524288;               // 49152
  float* dlt  = xd + 49152;               // 524288
  float* yb   = dlt + 524288;             // 524288
  float* co   = yb + 524288;              // 524288
  float* part = co + 524288;              // 256

  // fp32 param views into the pack
  const float* w_in  = pp + 0;
  const float* b_in  = pp + 16384;
  const float* w_out = pp + 391552;
  const float* b_out = pp + 392064;
  const float* gn_g[2], *gn_b[2], *inproj_w[2], *conv_w[2], *conv_b[2],
             *xproj_w[2], *dtp_w[2], *dtp_b[2], *alog_f[2], *dd_f[2];
  for (int k = 0; k < 2; ++k) {
    const float* base = pp + 16512 + (size_t)k * 187520;
    gn_g[k] = base + 0;       gn_b[k] = base + 128;
    inproj_w[k] = base + 256; conv_w[k] = base + 4864;
    conv_b[k] = base + 5120;  xproj_w[k] = base + 5248;
    dtp_w[k] = base + 103552; dtp_b[k] = base + 169088;
    alog_f[k] = base + 170112; dd_f[k] = base + 186496;
  }

  convert_params_kernel<<<(TOTAL_PARAMS + 255) / 256, 256, 0, stream>>>(pk, alog_raw, pp);
  conv_in_kernel<<<512, 256, 0, stream>>>(x, alog_raw, w_in, b_in, h0);

  float* hbuf[2] = { h0, h1 };
  for (int blk = 0; blk < 2; ++blk) {
    float* hin  = hbuf[blk & 1];
    float* hout = hbuf[(blk + 1) & 1];
    gn_stats1<<<128, 256, 0, stream>>>(hin, part);
    fused_u_kernel<<<256, 256, 0, stream>>>(hin, part, gn_g[blk], gn_b[blk],
                                            inproj_w[blk], conv_w[blk], conv_b[blk], u);
    xdbl_delta_kernel<<<512, 256, 0, stream>>>(u, xproj_w[blk], dtp_w[blk], dtp_b[blk], xd, dlt);
    scan_kernel<<<256, 256, 0, stream>>>(u, dlt, xd, alog_f[blk], dd_f[blk], yb);
    merge_res_kernel<<<256, 256, 0, stream>>>(hin, part, gn_g[blk], gn_b[blk],
                                              inproj_w[blk], yb, hout);
  }

  convout_kernel<<<2048, 256, 0, stream>>>(h0, w_out, b_out, co);
  resize_kernel<<<32768, 256, 0, stream>>>(co, alog_raw, d_out);
}